// Round 9
// baseline (28701.688 us; speedup 1.0000x reference)
//
#include <hip/hip_runtime.h>
#include <hip/hip_bf16.h>

#define HID 1024
#define BATCH 128
#define TSTEPS 512
#define NWG 256
#define NTHR 1024

typedef __bf16 bf16x4 __attribute__((ext_vector_type(4)));
typedef __bf16 bf16x8 __attribute__((ext_vector_type(8)));
typedef float f32x4 __attribute__((ext_vector_type(4)));

#define ASTORE_U(p,v) __hip_atomic_store((p),(v),__ATOMIC_RELAXED,__HIP_MEMORY_SCOPE_AGENT)
#define ASTORE_F(p,v) __hip_atomic_store((p),(v),__ATOMIC_RELAXED,__HIP_MEMORY_SCOPE_AGENT)
#define ALOAD_U(p)    __hip_atomic_load((p),__ATOMIC_RELAXED,__HIP_MEMORY_SCOPE_AGENT)
#define ALOAD_F(p)    __hip_atomic_load((p),__ATOMIC_RELAXED,__HIP_MEMORY_SCOPE_AGENT)
#define ALOAD_ULL(p)  __hip_atomic_load((p),__ATOMIC_RELAXED,__HIP_MEMORY_SCOPE_AGENT)
#define AADD_U(p,v)   __hip_atomic_fetch_add((p),(v),__ATOMIC_RELAXED,__HIP_MEMORY_SCOPE_AGENT)

__device__ __forceinline__ float sigm(float x){ return 1.f/(1.f+__expf(-x)); }

__device__ __forceinline__ bf16x8 cvt8(const float* __restrict__ p){
  bf16x8 r;
  #pragma unroll
  for (int i=0;i<8;i++) r[i] = (__bf16)p[i];
  return r;
}
__device__ __forceinline__ bf16x8 cvt8s(const float* __restrict__ p, float s){
  bf16x8 r;
  #pragma unroll
  for (int i=0;i<8;i++) r[i] = (__bf16)(p[i]*s);
  return r;
}

// staging layout (round-6 proven): element (u,b) at  (u>>2)*512 + b*4 + (u&3)  [bf16]
__global__ void init_kernel(const float* __restrict__ z,
                            unsigned short* __restrict__ st0,
                            unsigned* __restrict__ bar){
  int i = blockIdx.x*blockDim.x + threadIdx.x;     // 65536 threads
  if (i < 1024) bar[i] = 0u;
  for (int idx = i; idx < BATCH*HID; idx += 65536){
    int blk = idx >> 9, rem = idx & 511, b = rem >> 2, du = rem & 3;
    st0[idx] = __builtin_bit_cast(unsigned short, (__bf16)z[b*HID + blk*4 + du]);
  }
}

// barrier word offsets, each slot in its own 128B line, all < 1024 words (4KB)
#define GRP_CTR(g)  ((g)*32)
#define MID_CTR     256
#define GRP_FLAG(g) (320 + (g)*32)

// NOTE: no min-waves arg — with a 1024-thread block the backend must fit one
// block/CU (4 waves/SIMD) -> VGPR cap 128. Round 8's (1024,4) made the
// compiler target 8 waves/SIMD -> 64 VGPR -> acc/weight spill to scratch
// (FETCH 28GB, WRITE 11.5GB). This is the single change vs round 8.
__global__ __launch_bounds__(NTHR) void lstm_kernel(
    const float* __restrict__ seq,
    const float* __restrict__ z,
    const float* __restrict__ Wih0, const float* __restrict__ Whh0,
    const float* __restrict__ bih0, const float* __restrict__ bhh0,
    const float* __restrict__ Wih1, const float* __restrict__ Whh1,
    const float* __restrict__ bih1, const float* __restrict__ bhh1,
    const float* __restrict__ Wout, const float* __restrict__ bout,
    float* __restrict__ out,
    unsigned short* __restrict__ st0,
    unsigned short* __restrict__ st1,
    float* __restrict__ predpart,   // [wg][b]
    float* __restrict__ shalf,      // [b] upper-half partial sums
    float* __restrict__ losspart,
    unsigned* __restrict__ bar)
{
  const int tid  = threadIdx.x;
  const int wg   = blockIdx.x;
  const int wid  = tid >> 6;        // 0..15 (16 waves, K=64 slice each)
  const int lane = tid & 63;
  const int u0   = wg << 2;         // owns units [u0,u0+4) in both layers

  __shared__ float red[8][2048];    // K-partials, XOR-skewed; two-stage (8 write + 8 add)
  __shared__ float finals2[16*132]; // [col][b], padded stride 132
  __shared__ float pr2[2];
  __shared__ float sb0p[16], sb0f[16], sb1[16];

  const float bout_s = bout[0];

  if (tid < 16) {
    int g = tid >> 2, du = tid & 3;
    int gc = g*HID + u0 + du;
    float bp = bih0[gc] + bhh0[gc];
    sb0p[tid] = bp;                       // layer0 bias, t==0 (pred = 0)
    sb0f[tid] = bp + Wih0[gc]*bout_s;     // layer0 bias + folded b_out term
    sb1[tid]  = bih1[gc] + bhh1[gc];
  }

  // elementwise cell mapping (threads 0..511 only): thread -> (batch eb, unit edu)
  const int eb  = tid >> 2;
  const int edu = tid & 3;
  const float wout_u = Wout[u0 + edu];
  float c0 = 0.f, c1 = 0.f;
  if (tid < 512) { c0 = z[eb*HID + u0 + edu]; c1 = c0; }
  float lossacc = 0.f;
  float myhalf  = 0.f;                    // thread0 of wg<128: lower-half pred sum

  // ---- persistent weight fragments (MFMA B-operand layout), K=64 per wave ----
  const int bcol = lane & 15;
  const int gcol = (bcol >> 2)*HID + u0 + (bcol & 3);
  const int ksub = (lane >> 4) << 3;
  bf16x8 w_hh0[2], w_ih1[2], w_hh1[2], w_fold[2];
  {
    const float wih0c = Wih0[gcol];
    #pragma unroll
    for (int kt=0; kt<2; ++kt) {
      int k0 = (wid << 6) + (kt << 5) + ksub;   // wave's K-slice [wid*64, wid*64+64)
      w_hh0[kt]  = cvt8(Whh0 + gcol*HID + k0);
      w_ih1[kt]  = cvt8(Wih1 + gcol*HID + k0);
      w_hh1[kt]  = cvt8(Whh1 + gcol*HID + k0);
      w_fold[kt] = cvt8s(Wout + k0, wih0c);
    }
  }

  f32x4 accG0[8], accG1[8];
  #pragma unroll
  for (int m=0;m<8;m++){ accG0[m] = f32x4{0,0,0,0}; accG1[m] = f32x4{0,0,0,0}; }

  unsigned gen = 0;

  const int rowoff = (lane & 15) * 4;
  const int blk0   = (wid << 4) + ((lane >> 4) << 1);

  // sc1 (coherence-point) 8B loads; 16 waves / 4 per SIMD hide the L3 latency.
  auto do_pass = [&](const unsigned short* __restrict__ src,
                     const bf16x8* wA, const bf16x8* wB,
                     f32x4* accA, f32x4* accB){
    #pragma unroll
    for (int kt=0; kt<2; ++kt){
      const unsigned short* pk = src + (size_t)((blk0 + kt*8)*512) + rowoff;
      #pragma unroll
      for (int g4=0; g4<2; ++g4){             // groups of 4 frags: af live-range 16 VGPR
        bf16x8 af[4];
        #pragma unroll
        for (int m=0;m<4;m++){
          const unsigned short* p = pk + (g4*4 + m)*64;
          unsigned long long lo64 = ALOAD_ULL((const unsigned long long*)p);
          unsigned long long hi64 = ALOAD_ULL((const unsigned long long*)(p + 512));
          bf16x4 lo = __builtin_bit_cast(bf16x4, lo64);
          bf16x4 hi = __builtin_bit_cast(bf16x4, hi64);
          af[m] = __builtin_shufflevector(lo, hi, 0,1,2,3,4,5,6,7);
        }
        #pragma unroll
        for (int m=0;m<4;m++){
          int mm = g4*4 + m;
          accA[mm] = __builtin_amdgcn_mfma_f32_16x16x32_bf16(af[m], wA[kt], accA[mm], 0, 0, 0);
          accB[mm] = __builtin_amdgcn_mfma_f32_16x16x32_bf16(af[m], wB[kt], accB[mm], 0, 0, 0);
        }
      }
    }
  };

  // 16 wave K-partials -> finals2[col][b] (+bias); two-stage, XOR skew (bijective).
  auto reduce_finals = [&](f32x4* acc, const float* sbias){
    const int lrow = lane >> 4;
    const int wbase0 = (lrow << 6) + (lane & 15);
    const int skw = lrow << 3;
    if (wid < 8) {
      #pragma unroll
      for (int m=0;m<8;m++){
        #pragma unroll
        for (int e=0;e<4;e++)
          red[wid][(wbase0 + (e<<4) + (m<<8)) ^ skw] = acc[m][e];
      }
    }
    __syncthreads();
    if (wid >= 8) {
      #pragma unroll
      for (int m=0;m<8;m++){
        #pragma unroll
        for (int e=0;e<4;e++)
          red[wid-8][(wbase0 + (e<<4) + (m<<8)) ^ skw] += acc[m][e];
      }
    }
    __syncthreads();
    #pragma unroll
    for (int j=0;j<2;j++){
      int i = tid + j*1024;
      int a = i ^ ((((i>>6)&3))<<3);
      float s = red[0][a]+red[1][a]+red[2][a]+red[3][a]
              + red[4][a]+red[5][a]+red[6][a]+red[7][a] + sbias[i&15];
      finals2[(i&15)*132 + (i>>4)] = s;
    }
    __syncthreads();
    #pragma unroll
    for (int m=0;m<8;m++) acc[m] = f32x4{0,0,0,0};
  };

  auto elementwise = [&](float& c, unsigned short* __restrict__ stdst, bool dopred){
    if (tid < 512) {
      float gi = finals2[(edu   )*132 + eb];
      float gf = finals2[(edu+ 4)*132 + eb];
      float gg = finals2[(edu+ 8)*132 + eb];
      float go = finals2[(edu+12)*132 + eb];
      float fi = sigm(gi), ff = sigm(gf), fo = sigm(go);
      c = ff*c + fi*tanhf(gg);
      float h = fo*tanhf(c);
      unsigned h16 = (unsigned)__builtin_bit_cast(unsigned short, (__bf16)h);
      unsigned other = (unsigned)__shfl_xor((int)h16, 1);
      if (!(tid & 1)) {
        unsigned word = h16 | (other << 16);          // coalesced dword at elem tid
        ASTORE_U((unsigned*)(stdst + wg*512 + tid), word);
      }
      if (dopred){
        float pv = h * wout_u;                        // fp32 pred partial (pre-quant h)
        pv += __shfl_xor(pv, 1);
        pv += __shfl_xor(pv, 2);
        if (edu == 0) ASTORE_F(&predpart[wg*128 + eb], pv);
      }
    }
  };

  // padded counters, fan-out release. No cache-maintenance anywhere: all cross-WG
  // data moves via sc1 stores (drained by __syncthreads) + sc1 loads.
  auto grid_barrier = [&](){
    __syncthreads();
    ++gen;
    if (tid == 0) {
      unsigned old = AADD_U(&bar[GRP_CTR(wg & 7)], 1u);
      if (old == gen*32u - 1u) {
        unsigned r = AADD_U(&bar[MID_CTR], 1u);
        if (r == gen*8u - 1u) {
          #pragma unroll
          for (int g2=0; g2<8; ++g2) ASTORE_U(&bar[GRP_FLAG(g2)], gen);
        }
      }
      while (ALOAD_U(&bar[GRP_FLAG(wg & 7)]) < gen)
        __builtin_amdgcn_s_sleep(2);
    }
    __syncthreads();
  };

  // ---- prologue: accG0 = z@Whh0 (gates0[0]); accG1 = z@Whh1 (carry) ----
  do_pass(st0, w_hh0, w_hh1, accG0, accG1);
  grid_barrier();                          // all WGs consumed z-staging
  reduce_finals(accG0, sb0p);
  elementwise(c0, st0, false);             // h0[0] -> st0
  grid_barrier();                          // publish h0[0]

  for (int t=0; t<TSTEPS; ++t) {
    // ---- Phase A: gates1[t] completes; gates0[t+1] h0-part ----
    do_pass(st0, w_ih1, w_hh0, accG1, accG0);
    float oh = 0.f;
    if (t > 0 && wg < BATCH && tid == 0) oh = ALOAD_F(&shalf[wg]);   // early load
    reduce_finals(accG1, sb1);
    if (t > 0 && wg < BATCH && tid == 0) {
      float pred = myhalf + oh + bout_s;                   // finalize pred[t-1]
      out[1 + wg*TSTEPS + (t-1)] = pred;
      float d = seq[wg*TSTEPS + (t-1)] - pred;
      lossacc += d*d;
    }
    elementwise(c1, st1, true);            // h1[t] + pred partials
    grid_barrier();                        // publish h1[t], predpart

    // ---- Phase B: gates0[t+1] completes via fold; gates1[t+1] h1-part ----
    float hred = 0.f;
    if (tid < 128)
      hred = ALOAD_F(&predpart[((wg >> 7)*128 + tid)*128 + (wg & 127)]);  // early
    do_pass(st1, w_fold, w_hh1, accG0, accG1);
    hred += __shfl_xor(hred, 1);  hred += __shfl_xor(hred, 2);
    hred += __shfl_xor(hred, 4);  hred += __shfl_xor(hred, 8);
    hred += __shfl_xor(hred, 16); hred += __shfl_xor(hred, 32);
    if (tid == 0)  pr2[0] = hred;
    if (tid == 64) pr2[1] = hred;
    reduce_finals(accG0, sb0f);            // internal syncs publish pr2 to tid0
    if (tid == 0) {
      float hs = pr2[0] + pr2[1];
      if (wg >= BATCH) ASTORE_F(&shalf[wg - BATCH], hs);
      else             myhalf = hs;
    }
    elementwise(c0, st0, false);           // h0[t+1]
    grid_barrier();                        // publish h0[t+1], shalf
  }

  // ---- epilogue: last pred + loss ----
  if (wg < BATCH && tid == 0) {
    float oh2 = ALOAD_F(&shalf[wg]);
    float pred = myhalf + oh2 + bout_s;
    out[1 + wg*TSTEPS + (TSTEPS-1)] = pred;
    float d = seq[wg*TSTEPS + (TSTEPS-1)] - pred;
    lossacc += d*d;
    ASTORE_F(&losspart[wg], lossacc);
  }
  grid_barrier();
  if (wg == 0) {
    float v = 0.f;
    if (tid < BATCH) v = ALOAD_F(&losspart[tid]);
    v += __shfl_xor(v, 1);  v += __shfl_xor(v, 2);
    v += __shfl_xor(v, 4);  v += __shfl_xor(v, 8);
    v += __shfl_xor(v, 16); v += __shfl_xor(v, 32);
    if (tid == 0)  pr2[0] = v;
    if (tid == 64) pr2[1] = v;
    __syncthreads();
    if (tid == 0) out[0] = (pr2[0] + pr2[1]) * (1.f/65536.f);
  }
}

extern "C" void kernel_launch(void* const* d_in, const int* in_sizes, int n_in,
                              void* d_out, int out_size, void* d_ws, size_t ws_size,
                              hipStream_t stream)
{
  const float* seq  = (const float*)d_in[0];
  const float* z    = (const float*)d_in[1];
  const float* Wih0 = (const float*)d_in[2];
  const float* Whh0 = (const float*)d_in[3];
  const float* bih0 = (const float*)d_in[4];
  const float* bhh0 = (const float*)d_in[5];
  const float* Wih1 = (const float*)d_in[6];
  const float* Whh1 = (const float*)d_in[7];
  const float* bih1 = (const float*)d_in[8];
  const float* bhh1 = (const float*)d_in[9];
  const float* Wout = (const float*)d_in[10];
  const float* bout = (const float*)d_in[11];
  float* out = (float*)d_out;

  // round-6-proven layout
  char* ws = (char*)d_ws;
  unsigned short* st0 = (unsigned short*)(ws);                    // 256KB @ 0
  unsigned short* st1 = (unsigned short*)(ws + 256*1024);         // 256KB @ 256K
  unsigned* bar   = (unsigned*)(ws + 512*1024);                   // 4KB  @ 512K
  float* predpart = (float*)(ws + 516*1024);                      // 128KB @ 516K
  float* shalf    = (float*)(ws + 644*1024);                      // 512B @ 644K
  float* losspart = (float*)(ws + 644*1024 + 512);                // 512B

  hipLaunchKernelGGL(init_kernel, dim3(256), dim3(256), 0, stream, z, st0, bar);

  void* args[] = { (void*)&seq, (void*)&z, (void*)&Wih0, (void*)&Whh0, (void*)&bih0, (void*)&bhh0,
                   (void*)&Wih1, (void*)&Whh1, (void*)&bih1, (void*)&bhh1, (void*)&Wout, (void*)&bout,
                   (void*)&out, (void*)&st0, (void*)&st1, (void*)&predpart, (void*)&shalf,
                   (void*)&losspart, (void*)&bar };
  hipLaunchCooperativeKernel((void*)lstm_kernel, dim3(NWG), dim3(NTHR), args, 0u, stream);
}

// Round 10
// 27894.592 us; speedup vs baseline: 1.0289x; 1.0289x over previous
//
#include <hip/hip_runtime.h>
#include <hip/hip_bf16.h>

#define HID 1024
#define BATCH 128
#define TSTEPS 512
#define NWG 256
#define NTHR 1024

typedef __bf16 bf16x4 __attribute__((ext_vector_type(4)));
typedef __bf16 bf16x8 __attribute__((ext_vector_type(8)));
typedef float f32x4 __attribute__((ext_vector_type(4)));

#define ASTORE_U(p,v) __hip_atomic_store((p),(v),__ATOMIC_RELAXED,__HIP_MEMORY_SCOPE_AGENT)
#define ASTORE_F(p,v) __hip_atomic_store((p),(v),__ATOMIC_RELAXED,__HIP_MEMORY_SCOPE_AGENT)
#define ALOAD_U(p)    __hip_atomic_load((p),__ATOMIC_RELAXED,__HIP_MEMORY_SCOPE_AGENT)
#define ALOAD_F(p)    __hip_atomic_load((p),__ATOMIC_RELAXED,__HIP_MEMORY_SCOPE_AGENT)
#define ALOAD_ULL(p)  __hip_atomic_load((p),__ATOMIC_RELAXED,__HIP_MEMORY_SCOPE_AGENT)
#define AADD_U(p,v)   __hip_atomic_fetch_add((p),(v),__ATOMIC_RELAXED,__HIP_MEMORY_SCOPE_AGENT)

__device__ __forceinline__ float sigm(float x){ return 1.f/(1.f+__expf(-x)); }

__device__ __forceinline__ bf16x8 cvt8(const float* __restrict__ p){
  bf16x8 r;
  #pragma unroll
  for (int i=0;i<8;i++) r[i] = (__bf16)p[i];
  return r;
}
__device__ __forceinline__ bf16x8 cvt8s(const float* __restrict__ p, float s){
  bf16x8 r;
  #pragma unroll
  for (int i=0;i<8;i++) r[i] = (__bf16)(p[i]*s);
  return r;
}

// staging layout (round-6 proven): element (u,b) at  (u>>2)*512 + b*4 + (u&3)  [bf16]
__global__ void init_kernel(const float* __restrict__ z,
                            unsigned short* __restrict__ st0,
                            unsigned* __restrict__ bar){
  int i = blockIdx.x*blockDim.x + threadIdx.x;     // 65536 threads
  if (i < 1024) bar[i] = 0u;
  for (int idx = i; idx < BATCH*HID; idx += 65536){
    int blk = idx >> 9, rem = idx & 511, b = rem >> 2, du = rem & 3;
    st0[idx] = __builtin_bit_cast(unsigned short, (__bf16)z[b*HID + blk*4 + du]);
  }
}

// barrier word offsets, each slot in its own 128B line, all < 1024 words (4KB)
#define GRP_CTR(g)  ((g)*32)
#define MID_CTR     256
#define GRP_FLAG(g) (320 + (g)*32)

// waves_per_eu(4,4): pin allocator to EXACTLY 4 waves/EU -> 128 VGPR budget.
// Rounds 8/9 proved launch_bounds alone lets the heuristic pick 64 VGPR
// (8 waves/EU target) and spill the MFMA accumulators (~30GB/dispatch).
__global__ __launch_bounds__(NTHR)
__attribute__((amdgpu_waves_per_eu(4, 4)))
void lstm_kernel(
    const float* __restrict__ seq,
    const float* __restrict__ z,
    const float* __restrict__ Wih0, const float* __restrict__ Whh0,
    const float* __restrict__ bih0, const float* __restrict__ bhh0,
    const float* __restrict__ Wih1, const float* __restrict__ Whh1,
    const float* __restrict__ bih1, const float* __restrict__ bhh1,
    const float* __restrict__ Wout, const float* __restrict__ bout,
    float* __restrict__ out,
    unsigned short* __restrict__ st0,
    unsigned short* __restrict__ st1,
    float* __restrict__ predpart,   // [wg][b]
    float* __restrict__ shalf,      // [b] upper-half partial sums
    float* __restrict__ losspart,
    unsigned* __restrict__ bar)
{
  const int tid  = threadIdx.x;
  const int wg   = blockIdx.x;
  const int wid  = tid >> 6;        // 0..15 (16 waves, K=64 slice each)
  const int lane = tid & 63;
  const int u0   = wg << 2;         // owns units [u0,u0+4) in both layers

  __shared__ float red[8][2048];    // K-partials, XOR-skewed; two-stage (8 write + 8 add)
  __shared__ float finals2[16*132]; // [col][b], padded stride 132
  __shared__ float pr2[2];
  __shared__ float sb0p[16], sb0f[16], sb1[16];

  const float bout_s = bout[0];

  if (tid < 16) {
    int g = tid >> 2, du = tid & 3;
    int gc = g*HID + u0 + du;
    float bp = bih0[gc] + bhh0[gc];
    sb0p[tid] = bp;                       // layer0 bias, t==0 (pred = 0)
    sb0f[tid] = bp + Wih0[gc]*bout_s;     // layer0 bias + folded b_out term
    sb1[tid]  = bih1[gc] + bhh1[gc];
  }

  // elementwise cell mapping (threads 0..511 only): thread -> (batch eb, unit edu)
  const int eb  = tid >> 2;
  const int edu = tid & 3;
  const float wout_u = Wout[u0 + edu];
  float c0 = 0.f, c1 = 0.f;
  if (tid < 512) { c0 = z[eb*HID + u0 + edu]; c1 = c0; }
  float lossacc = 0.f;
  float myhalf  = 0.f;                    // thread0 of wg<128: lower-half pred sum

  // ---- persistent weight fragments (MFMA B-operand layout), K=64 per wave ----
  const int bcol = lane & 15;
  const int gcol = (bcol >> 2)*HID + u0 + (bcol & 3);
  const int ksub = (lane >> 4) << 3;
  bf16x8 w_hh0[2], w_ih1[2], w_hh1[2], w_fold[2];
  {
    const float wih0c = Wih0[gcol];
    #pragma unroll
    for (int kt=0; kt<2; ++kt) {
      int k0 = (wid << 6) + (kt << 5) + ksub;   // wave's K-slice [wid*64, wid*64+64)
      w_hh0[kt]  = cvt8(Whh0 + gcol*HID + k0);
      w_ih1[kt]  = cvt8(Wih1 + gcol*HID + k0);
      w_hh1[kt]  = cvt8(Whh1 + gcol*HID + k0);
      w_fold[kt] = cvt8s(Wout + k0, wih0c);
    }
  }

  f32x4 accG0[8], accG1[8];
  #pragma unroll
  for (int m=0;m<8;m++){ accG0[m] = f32x4{0,0,0,0}; accG1[m] = f32x4{0,0,0,0}; }

  unsigned gen = 0;

  const int rowoff = (lane & 15) * 4;
  const int blk0   = (wid << 4) + ((lane >> 4) << 1);

  // sc1 (coherence-point) 8B loads; 16 waves / 4 per SIMD hide the L3 latency.
  auto do_pass = [&](const unsigned short* __restrict__ src,
                     const bf16x8* wA, const bf16x8* wB,
                     f32x4* accA, f32x4* accB){
    #pragma unroll
    for (int kt=0; kt<2; ++kt){
      const unsigned short* pk = src + (size_t)((blk0 + kt*8)*512) + rowoff;
      #pragma unroll
      for (int g4=0; g4<2; ++g4){             // groups of 4 frags: af live-range 16 VGPR
        bf16x8 af[4];
        #pragma unroll
        for (int m=0;m<4;m++){
          const unsigned short* p = pk + (g4*4 + m)*64;
          unsigned long long lo64 = ALOAD_ULL((const unsigned long long*)p);
          unsigned long long hi64 = ALOAD_ULL((const unsigned long long*)(p + 512));
          bf16x4 lo = __builtin_bit_cast(bf16x4, lo64);
          bf16x4 hi = __builtin_bit_cast(bf16x4, hi64);
          af[m] = __builtin_shufflevector(lo, hi, 0,1,2,3,4,5,6,7);
        }
        #pragma unroll
        for (int m=0;m<4;m++){
          int mm = g4*4 + m;
          accA[mm] = __builtin_amdgcn_mfma_f32_16x16x32_bf16(af[m], wA[kt], accA[mm], 0, 0, 0);
          accB[mm] = __builtin_amdgcn_mfma_f32_16x16x32_bf16(af[m], wB[kt], accB[mm], 0, 0, 0);
        }
      }
    }
  };

  // 16 wave K-partials -> finals2[col][b] (+bias); two-stage, XOR skew (bijective).
  auto reduce_finals = [&](f32x4* acc, const float* sbias){
    const int lrow = lane >> 4;
    const int wbase0 = (lrow << 6) + (lane & 15);
    const int skw = lrow << 3;
    if (wid < 8) {
      #pragma unroll
      for (int m=0;m<8;m++){
        #pragma unroll
        for (int e=0;e<4;e++)
          red[wid][(wbase0 + (e<<4) + (m<<8)) ^ skw] = acc[m][e];
      }
    }
    __syncthreads();
    if (wid >= 8) {
      #pragma unroll
      for (int m=0;m<8;m++){
        #pragma unroll
        for (int e=0;e<4;e++)
          red[wid-8][(wbase0 + (e<<4) + (m<<8)) ^ skw] += acc[m][e];
      }
    }
    __syncthreads();
    #pragma unroll
    for (int j=0;j<2;j++){
      int i = tid + j*1024;
      int a = i ^ ((((i>>6)&3))<<3);
      float s = red[0][a]+red[1][a]+red[2][a]+red[3][a]
              + red[4][a]+red[5][a]+red[6][a]+red[7][a] + sbias[i&15];
      finals2[(i&15)*132 + (i>>4)] = s;
    }
    __syncthreads();
    #pragma unroll
    for (int m=0;m<8;m++) acc[m] = f32x4{0,0,0,0};
  };

  auto elementwise = [&](float& c, unsigned short* __restrict__ stdst, bool dopred){
    if (tid < 512) {
      float gi = finals2[(edu   )*132 + eb];
      float gf = finals2[(edu+ 4)*132 + eb];
      float gg = finals2[(edu+ 8)*132 + eb];
      float go = finals2[(edu+12)*132 + eb];
      float fi = sigm(gi), ff = sigm(gf), fo = sigm(go);
      c = ff*c + fi*tanhf(gg);
      float h = fo*tanhf(c);
      unsigned h16 = (unsigned)__builtin_bit_cast(unsigned short, (__bf16)h);
      unsigned other = (unsigned)__shfl_xor((int)h16, 1);
      if (!(tid & 1)) {
        unsigned word = h16 | (other << 16);          // coalesced dword at elem tid
        ASTORE_U((unsigned*)(stdst + wg*512 + tid), word);
      }
      if (dopred){
        float pv = h * wout_u;                        // fp32 pred partial (pre-quant h)
        pv += __shfl_xor(pv, 1);
        pv += __shfl_xor(pv, 2);
        if (edu == 0) ASTORE_F(&predpart[wg*128 + eb], pv);
      }
    }
  };

  // padded counters, fan-out release. No cache-maintenance anywhere: all cross-WG
  // data moves via sc1 stores (drained by __syncthreads) + sc1 loads.
  auto grid_barrier = [&](){
    __syncthreads();
    ++gen;
    if (tid == 0) {
      unsigned old = AADD_U(&bar[GRP_CTR(wg & 7)], 1u);
      if (old == gen*32u - 1u) {
        unsigned r = AADD_U(&bar[MID_CTR], 1u);
        if (r == gen*8u - 1u) {
          #pragma unroll
          for (int g2=0; g2<8; ++g2) ASTORE_U(&bar[GRP_FLAG(g2)], gen);
        }
      }
      while (ALOAD_U(&bar[GRP_FLAG(wg & 7)]) < gen)
        __builtin_amdgcn_s_sleep(2);
    }
    __syncthreads();
  };

  // ---- prologue: accG0 = z@Whh0 (gates0[0]); accG1 = z@Whh1 (carry) ----
  do_pass(st0, w_hh0, w_hh1, accG0, accG1);
  grid_barrier();                          // all WGs consumed z-staging
  reduce_finals(accG0, sb0p);
  elementwise(c0, st0, false);             // h0[0] -> st0
  grid_barrier();                          // publish h0[0]

  for (int t=0; t<TSTEPS; ++t) {
    // ---- Phase A: gates1[t] completes; gates0[t+1] h0-part ----
    do_pass(st0, w_ih1, w_hh0, accG1, accG0);
    float oh = 0.f;
    if (t > 0 && wg < BATCH && tid == 0) oh = ALOAD_F(&shalf[wg]);   // early load
    reduce_finals(accG1, sb1);
    if (t > 0 && wg < BATCH && tid == 0) {
      float pred = myhalf + oh + bout_s;                   // finalize pred[t-1]
      out[1 + wg*TSTEPS + (t-1)] = pred;
      float d = seq[wg*TSTEPS + (t-1)] - pred;
      lossacc += d*d;
    }
    elementwise(c1, st1, true);            // h1[t] + pred partials
    grid_barrier();                        // publish h1[t], predpart

    // ---- Phase B: gates0[t+1] completes via fold; gates1[t+1] h1-part ----
    float hred = 0.f;
    if (tid < 128)
      hred = ALOAD_F(&predpart[((wg >> 7)*128 + tid)*128 + (wg & 127)]);  // early
    do_pass(st1, w_fold, w_hh1, accG0, accG1);
    hred += __shfl_xor(hred, 1);  hred += __shfl_xor(hred, 2);
    hred += __shfl_xor(hred, 4);  hred += __shfl_xor(hred, 8);
    hred += __shfl_xor(hred, 16); hred += __shfl_xor(hred, 32);
    if (tid == 0)  pr2[0] = hred;
    if (tid == 64) pr2[1] = hred;
    reduce_finals(accG0, sb0f);            // internal syncs publish pr2 to tid0
    if (tid == 0) {
      float hs = pr2[0] + pr2[1];
      if (wg >= BATCH) ASTORE_F(&shalf[wg - BATCH], hs);
      else             myhalf = hs;
    }
    elementwise(c0, st0, false);           // h0[t+1]
    grid_barrier();                        // publish h0[t+1], shalf
  }

  // ---- epilogue: last pred + loss ----
  if (wg < BATCH && tid == 0) {
    float oh2 = ALOAD_F(&shalf[wg]);
    float pred = myhalf + oh2 + bout_s;
    out[1 + wg*TSTEPS + (TSTEPS-1)] = pred;
    float d = seq[wg*TSTEPS + (TSTEPS-1)] - pred;
    lossacc += d*d;
    ASTORE_F(&losspart[wg], lossacc);
  }
  grid_barrier();
  if (wg == 0) {
    float v = 0.f;
    if (tid < BATCH) v = ALOAD_F(&losspart[tid]);
    v += __shfl_xor(v, 1);  v += __shfl_xor(v, 2);
    v += __shfl_xor(v, 4);  v += __shfl_xor(v, 8);
    v += __shfl_xor(v, 16); v += __shfl_xor(v, 32);
    if (tid == 0)  pr2[0] = v;
    if (tid == 64) pr2[1] = v;
    __syncthreads();
    if (tid == 0) out[0] = (pr2[0] + pr2[1]) * (1.f/65536.f);
  }
}

extern "C" void kernel_launch(void* const* d_in, const int* in_sizes, int n_in,
                              void* d_out, int out_size, void* d_ws, size_t ws_size,
                              hipStream_t stream)
{
  const float* seq  = (const float*)d_in[0];
  const float* z    = (const float*)d_in[1];
  const float* Wih0 = (const float*)d_in[2];
  const float* Whh0 = (const float*)d_in[3];
  const float* bih0 = (const float*)d_in[4];
  const float* bhh0 = (const float*)d_in[5];
  const float* Wih1 = (const float*)d_in[6];
  const float* Whh1 = (const float*)d_in[7];
  const float* bih1 = (const float*)d_in[8];
  const float* bhh1 = (const float*)d_in[9];
  const float* Wout = (const float*)d_in[10];
  const float* bout = (const float*)d_in[11];
  float* out = (float*)d_out;

  // round-6-proven layout
  char* ws = (char*)d_ws;
  unsigned short* st0 = (unsigned short*)(ws);                    // 256KB @ 0
  unsigned short* st1 = (unsigned short*)(ws + 256*1024);         // 256KB @ 256K
  unsigned* bar   = (unsigned*)(ws + 512*1024);                   // 4KB  @ 512K
  float* predpart = (float*)(ws + 516*1024);                      // 128KB @ 516K
  float* shalf    = (float*)(ws + 644*1024);                      // 512B @ 644K
  float* losspart = (float*)(ws + 644*1024 + 512);                // 512B

  hipLaunchKernelGGL(init_kernel, dim3(256), dim3(256), 0, stream, z, st0, bar);

  void* args[] = { (void*)&seq, (void*)&z, (void*)&Wih0, (void*)&Whh0, (void*)&bih0, (void*)&bhh0,
                   (void*)&Wih1, (void*)&Whh1, (void*)&bih1, (void*)&bhh1, (void*)&Wout, (void*)&bout,
                   (void*)&out, (void*)&st0, (void*)&st1, (void*)&predpart, (void*)&shalf,
                   (void*)&losspart, (void*)&bar };
  hipLaunchCooperativeKernel((void*)lstm_kernel, dim3(NWG), dim3(NTHR), args, 0u, stream);
}

// Round 11
// 11715.040 us; speedup vs baseline: 2.4500x; 2.3811x over previous
//
#include <hip/hip_runtime.h>
#include <hip/hip_bf16.h>

#define HID 1024
#define BATCH 128
#define TSTEPS 512
#define NWG 256
#define NTHR 512

typedef __bf16 bf16x4 __attribute__((ext_vector_type(4)));
typedef __bf16 bf16x8 __attribute__((ext_vector_type(8)));
typedef float f32x4 __attribute__((ext_vector_type(4)));

#define ASTORE_U(p,v) __hip_atomic_store((p),(v),__ATOMIC_RELAXED,__HIP_MEMORY_SCOPE_AGENT)
#define ASTORE_F(p,v) __hip_atomic_store((p),(v),__ATOMIC_RELAXED,__HIP_MEMORY_SCOPE_AGENT)
#define ALOAD_U(p)    __hip_atomic_load((p),__ATOMIC_RELAXED,__HIP_MEMORY_SCOPE_AGENT)
#define ALOAD_F(p)    __hip_atomic_load((p),__ATOMIC_RELAXED,__HIP_MEMORY_SCOPE_AGENT)
#define ALOAD_ULL(p)  __hip_atomic_load((p),__ATOMIC_RELAXED,__HIP_MEMORY_SCOPE_AGENT)
#define AADD_U(p,v)   __hip_atomic_fetch_add((p),(v),__ATOMIC_RELAXED,__HIP_MEMORY_SCOPE_AGENT)

__device__ __forceinline__ float sigm(float x){ return 1.f/(1.f+__expf(-x)); }

__device__ __forceinline__ bf16x8 cvt8(const float* __restrict__ p){
  bf16x8 r;
  #pragma unroll
  for (int i=0;i<8;i++) r[i] = (__bf16)p[i];
  return r;
}
__device__ __forceinline__ bf16x8 cvt8s(const float* __restrict__ p, float s){
  bf16x8 r;
  #pragma unroll
  for (int i=0;i<8;i++) r[i] = (__bf16)(p[i]*s);
  return r;
}

// staging layout (round-6 proven): element (u,b) at  (u>>2)*512 + b*4 + (u&3)  [bf16]
__global__ void init_kernel(const float* __restrict__ z,
                            unsigned short* __restrict__ st0,
                            unsigned* __restrict__ bar){
  int i = blockIdx.x*blockDim.x + threadIdx.x;     // 65536 threads
  if (i < 1024) bar[i] = 0u;
  for (int idx = i; idx < BATCH*HID; idx += 65536){
    int blk = idx >> 9, rem = idx & 511, b = rem >> 2, du = rem & 3;
    st0[idx] = __builtin_bit_cast(unsigned short, (__bf16)z[b*HID + blk*4 + du]);
  }
}

// 8 group counters, each in its own 128B line. No mid counter, no flags:
// release is detected by polling all 8 counters (monotone >= 32*gen).
#define GRP_CTR(g)  ((g)*32)

// 512 threads, 2 waves/EU min AND max -> 256-VGPR budget, no spill, 1 block/CU
// (8 waves x 256 VGPR = full RF). Rounds 8-10 proved 1024-thread blocks are
// stuck at 64 VGPR + spill; this is the proven 512-thread core with headroom.
__global__ __launch_bounds__(NTHR, 2)
__attribute__((amdgpu_waves_per_eu(2, 2)))
void lstm_kernel(
    const float* __restrict__ seq,
    const float* __restrict__ z,
    const float* __restrict__ Wih0, const float* __restrict__ Whh0,
    const float* __restrict__ bih0, const float* __restrict__ bhh0,
    const float* __restrict__ Wih1, const float* __restrict__ Whh1,
    const float* __restrict__ bih1, const float* __restrict__ bhh1,
    const float* __restrict__ Wout, const float* __restrict__ bout,
    float* __restrict__ out,
    unsigned short* __restrict__ st0,
    unsigned short* __restrict__ st1,
    float* __restrict__ predpart,   // [wg][b]
    float* __restrict__ shalf,      // [b] upper-half partial sums
    float* __restrict__ losspart,
    unsigned* __restrict__ bar)
{
  const int tid  = threadIdx.x;
  const int wg   = blockIdx.x;
  const int wid  = tid >> 6;
  const int lane = tid & 63;
  const int u0   = wg << 2;          // owns units [u0,u0+4) in both layers

  __shared__ float red[8][2048];     // 8 wave K-partials, XOR-skewed (bijective)
  __shared__ float finals2[16*132];  // [col][b], padded stride 132
  __shared__ float pr2[2];
  __shared__ float sb0p[16], sb0f[16], sb1[16];

  const float bout_s = bout[0];

  if (tid < 16) {
    int g = tid >> 2, du = tid & 3;
    int gc = g*HID + u0 + du;
    float bp = bih0[gc] + bhh0[gc];
    sb0p[tid] = bp;                       // layer0 bias, t==0 (pred = 0)
    sb0f[tid] = bp + Wih0[gc]*bout_s;     // layer0 bias + folded b_out term
    sb1[tid]  = bih1[gc] + bhh1[gc];
  }

  const int eb  = tid >> 2;
  const int edu = tid & 3;
  const float wout_u = Wout[u0 + edu];
  float c0 = z[eb*HID + u0 + edu];
  float c1 = c0;
  float lossacc = 0.f;
  float myhalf  = 0.f;                    // thread0 of wg<128: lower-half pred sum

  // ---- persistent weight fragments (MFMA B-operand layout), K=128 per wave ----
  const int bcol = lane & 15;
  const int gcol = (bcol >> 2)*HID + u0 + (bcol & 3);
  const int ksub = (lane >> 4) << 3;
  bf16x8 w_hh0[4], w_ih1[4], w_hh1[4], w_fold[4];
  {
    const float wih0c = Wih0[gcol];
    #pragma unroll
    for (int kt=0; kt<4; ++kt) {
      int k0 = (wid << 7) + (kt << 5) + ksub;
      w_hh0[kt]  = cvt8(Whh0 + gcol*HID + k0);
      w_ih1[kt]  = cvt8(Wih1 + gcol*HID + k0);
      w_hh1[kt]  = cvt8(Whh1 + gcol*HID + k0);
      w_fold[kt] = cvt8s(Wout + k0, wih0c);
    }
  }

  f32x4 accG0[8], accG1[8];
  #pragma unroll
  for (int m=0;m<8;m++){ accG0[m] = f32x4{0,0,0,0}; accG1[m] = f32x4{0,0,0,0}; }

  unsigned gen = 0;

  const int rowoff = (lane & 15) * 4;
  const int blk0   = wid*32 + (lane>>4)*2;

  // 16 sc1 (coherence-point) 8B loads for one kt's A-fragments.
  auto ld8 = [&](bf16x8* af, const unsigned short* __restrict__ src, int kt){
    #pragma unroll
    for (int m=0;m<8;m++){
      const unsigned short* p = src + (size_t)((blk0 + kt*8)*512 + m*64 + rowoff);
      unsigned long long lo64 = ALOAD_ULL((const unsigned long long*)p);
      unsigned long long hi64 = ALOAD_ULL((const unsigned long long*)(p + 512));
      bf16x4 lo = __builtin_bit_cast(bf16x4, lo64);
      bf16x4 hi = __builtin_bit_cast(bf16x4, hi64);
      af[m] = __builtin_shufflevector(lo, hi, 0,1,2,3,4,5,6,7);
    }
  };

  // 2-deep software pipeline: kt and kt+1 in flight while kt is consumed.
  // At the 256-VGPR budget (afA+afB=64, acc=64, weights=64) this fits without
  // spill; at round-6's 128 budget the compiler serialized 4 load rounds.
  auto do_pass = [&](const unsigned short* __restrict__ src,
                     const bf16x8* wA, const bf16x8* wB,
                     f32x4* accA, f32x4* accB){
    bf16x8 afA[8], afB[8];
    ld8(afA, src, 0);
    ld8(afB, src, 1);
    #pragma unroll
    for (int kt=0; kt<4; ++kt){
      const bf16x8* cur = (kt & 1) ? afB : afA;
      #pragma unroll
      for (int m=0;m<8;m++){
        accA[m] = __builtin_amdgcn_mfma_f32_16x16x32_bf16(cur[m], wA[kt], accA[m], 0, 0, 0);
        accB[m] = __builtin_amdgcn_mfma_f32_16x16x32_bf16(cur[m], wB[kt], accB[m], 0, 0, 0);
      }
      if (kt < 2) ld8((kt & 1) ? afB : afA, src, kt + 2);  // refill after last use
    }
  };

  // 8 wave K-partials -> finals2[col][b] (+bias); zeroes acc. XOR skew (bijective).
  auto reduce_finals = [&](f32x4* acc, const float* sbias){
    const int lrow = lane >> 4;
    const int wbase0 = (lrow << 6) + (lane & 15);
    const int skw = lrow << 3;
    #pragma unroll
    for (int m=0;m<8;m++){
      #pragma unroll
      for (int e=0;e<4;e++)
        red[wid][(wbase0 + (e<<4) + (m<<8)) ^ skw] = acc[m][e];
    }
    __syncthreads();
    #pragma unroll
    for (int j=0;j<4;j++){
      int i = tid + j*512;
      int a = i ^ ((((i>>6)&3))<<3);
      float s = red[0][a]+red[1][a]+red[2][a]+red[3][a]
              + red[4][a]+red[5][a]+red[6][a]+red[7][a] + sbias[i&15];
      finals2[(i&15)*132 + (i>>4)] = s;
    }
    __syncthreads();
    #pragma unroll
    for (int m=0;m<8;m++) acc[m] = f32x4{0,0,0,0};
  };

  auto elementwise = [&](float& c, unsigned short* __restrict__ stdst, bool dopred){
    float gi = finals2[(edu   )*132 + eb];
    float gf = finals2[(edu+ 4)*132 + eb];
    float gg = finals2[(edu+ 8)*132 + eb];
    float go = finals2[(edu+12)*132 + eb];
    float fi = sigm(gi), ff = sigm(gf), fo = sigm(go);
    c = ff*c + fi*tanhf(gg);
    float h = fo*tanhf(c);
    unsigned h16 = (unsigned)__builtin_bit_cast(unsigned short, (__bf16)h);
    unsigned other = (unsigned)__shfl_xor((int)h16, 1);
    if (!(tid & 1)) {
      unsigned word = h16 | (other << 16);            // coalesced dword at elem tid
      ASTORE_U((unsigned*)(stdst + wg*512 + tid), word);
    }
    if (dopred){
      float pv = h * wout_u;
      pv += __shfl_xor(pv, 1);
      pv += __shfl_xor(pv, 2);
      if (edu == 0) ASTORE_F(&predpart[wg*128 + eb], pv);
    }
  };

  // Flag-free barrier: arrive = 1 RMW on own 128B-padded group counter;
  // release = poll all 8 counters (monotone >= 32*gen; no mid, no fanout,
  // no reset -> run-ahead safe). Cross-WG data stays on the sc1 protocol.
  auto grid_barrier = [&](){
    __syncthreads();                       // drains vmcnt -> sc1 stores at L3
    ++gen;
    if (tid == 0) {
      AADD_U(&bar[GRP_CTR(wg & 7)], 1u);
      const unsigned target = gen * 32u;
      for (;;) {
        unsigned d0 = ALOAD_U(&bar[GRP_CTR(0)]);
        unsigned d1 = ALOAD_U(&bar[GRP_CTR(1)]);
        unsigned d2 = ALOAD_U(&bar[GRP_CTR(2)]);
        unsigned d3 = ALOAD_U(&bar[GRP_CTR(3)]);
        unsigned d4 = ALOAD_U(&bar[GRP_CTR(4)]);
        unsigned d5 = ALOAD_U(&bar[GRP_CTR(5)]);
        unsigned d6 = ALOAD_U(&bar[GRP_CTR(6)]);
        unsigned d7 = ALOAD_U(&bar[GRP_CTR(7)]);
        unsigned m01 = d0 < d1 ? d0 : d1;
        unsigned m23 = d2 < d3 ? d2 : d3;
        unsigned m45 = d4 < d5 ? d4 : d5;
        unsigned m67 = d6 < d7 ? d6 : d7;
        unsigned ma = m01 < m23 ? m01 : m23;
        unsigned mb = m45 < m67 ? m45 : m67;
        unsigned mn = ma < mb ? ma : mb;
        if (mn >= target) break;
        __builtin_amdgcn_s_sleep(1);
      }
    }
    __syncthreads();
  };

  // ---- prologue: accG0 = z@Whh0 (gates0[0]); accG1 = z@Whh1 (carry) ----
  do_pass(st0, w_hh0, w_hh1, accG0, accG1);
  grid_barrier();                          // all WGs consumed z-staging
  reduce_finals(accG0, sb0p);
  elementwise(c0, st0, false);             // h0[0] -> st0
  grid_barrier();                          // publish h0[0]

  for (int t=0; t<TSTEPS; ++t) {
    // ---- Phase A: gates1[t] completes; gates0[t+1] h0-part ----
    do_pass(st0, w_ih1, w_hh0, accG1, accG0);
    float oh = 0.f;
    if (t > 0 && wg < BATCH && tid == 0) oh = ALOAD_F(&shalf[wg]);   // early load
    reduce_finals(accG1, sb1);
    if (t > 0 && wg < BATCH && tid == 0) {
      float pred = myhalf + oh + bout_s;                   // finalize pred[t-1]
      out[1 + wg*TSTEPS + (t-1)] = pred;
      float d = seq[wg*TSTEPS + (t-1)] - pred;
      lossacc += d*d;
    }
    elementwise(c1, st1, true);            // h1[t] + pred partials
    grid_barrier();                        // publish h1[t], predpart

    // ---- Phase B: gates0[t+1] completes via fold; gates1[t+1] h1-part ----
    float hred = 0.f;
    if (tid < 128)
      hred = ALOAD_F(&predpart[((wg >> 7)*128 + tid)*128 + (wg & 127)]);  // early
    do_pass(st1, w_fold, w_hh1, accG0, accG1);
    hred += __shfl_xor(hred, 1);  hred += __shfl_xor(hred, 2);
    hred += __shfl_xor(hred, 4);  hred += __shfl_xor(hred, 8);
    hred += __shfl_xor(hred, 16); hred += __shfl_xor(hred, 32);
    if (tid == 0)  pr2[0] = hred;
    if (tid == 64) pr2[1] = hred;
    reduce_finals(accG0, sb0f);            // internal syncs publish pr2 to tid0
    if (tid == 0) {
      float hs = pr2[0] + pr2[1];
      if (wg >= BATCH) ASTORE_F(&shalf[wg - BATCH], hs);
      else             myhalf = hs;
    }
    elementwise(c0, st0, false);           // h0[t+1]
    grid_barrier();                        // publish h0[t+1], shalf
  }

  // ---- epilogue: last pred + loss ----
  if (wg < BATCH && tid == 0) {
    float oh2 = ALOAD_F(&shalf[wg]);
    float pred = myhalf + oh2 + bout_s;
    out[1 + wg*TSTEPS + (TSTEPS-1)] = pred;
    float d = seq[wg*TSTEPS + (TSTEPS-1)] - pred;
    lossacc += d*d;
    ASTORE_F(&losspart[wg], lossacc);
  }
  grid_barrier();
  if (wg == 0) {
    float v = 0.f;
    if (tid < BATCH) v = ALOAD_F(&losspart[tid]);
    v += __shfl_xor(v, 1);  v += __shfl_xor(v, 2);
    v += __shfl_xor(v, 4);  v += __shfl_xor(v, 8);
    v += __shfl_xor(v, 16); v += __shfl_xor(v, 32);
    if (tid == 0)  pr2[0] = v;
    if (tid == 64) pr2[1] = v;
    __syncthreads();
    if (tid == 0) out[0] = (pr2[0] + pr2[1]) * (1.f/65536.f);
  }
}

extern "C" void kernel_launch(void* const* d_in, const int* in_sizes, int n_in,
                              void* d_out, int out_size, void* d_ws, size_t ws_size,
                              hipStream_t stream)
{
  const float* seq  = (const float*)d_in[0];
  const float* z    = (const float*)d_in[1];
  const float* Wih0 = (const float*)d_in[2];
  const float* Whh0 = (const float*)d_in[3];
  const float* bih0 = (const float*)d_in[4];
  const float* bhh0 = (const float*)d_in[5];
  const float* Wih1 = (const float*)d_in[6];
  const float* Whh1 = (const float*)d_in[7];
  const float* bih1 = (const float*)d_in[8];
  const float* bhh1 = (const float*)d_in[9];
  const float* Wout = (const float*)d_in[10];
  const float* bout = (const float*)d_in[11];
  float* out = (float*)d_out;

  // round-6-proven layout
  char* ws = (char*)d_ws;
  unsigned short* st0 = (unsigned short*)(ws);                    // 256KB @ 0
  unsigned short* st1 = (unsigned short*)(ws + 256*1024);         // 256KB @ 256K
  unsigned* bar   = (unsigned*)(ws + 512*1024);                   // 4KB  @ 512K
  float* predpart = (float*)(ws + 516*1024);                      // 128KB @ 516K
  float* shalf    = (float*)(ws + 644*1024);                      // 512B @ 644K
  float* losspart = (float*)(ws + 644*1024 + 512);                // 512B

  hipLaunchKernelGGL(init_kernel, dim3(256), dim3(256), 0, stream, z, st0, bar);

  void* args[] = { (void*)&seq, (void*)&z, (void*)&Wih0, (void*)&Whh0, (void*)&bih0, (void*)&bhh0,
                   (void*)&Wih1, (void*)&Whh1, (void*)&bih1, (void*)&bhh1, (void*)&Wout, (void*)&bout,
                   (void*)&out, (void*)&st0, (void*)&st1, (void*)&predpart, (void*)&shalf,
                   (void*)&losspart, (void*)&bar };
  hipLaunchCooperativeKernel((void*)lstm_kernel, dim3(NWG), dim3(NTHR), args, 0u, stream);
}

// Round 12
// 6435.792 us; speedup vs baseline: 4.4597x; 1.8203x over previous
//
#include <hip/hip_runtime.h>
#include <hip/hip_bf16.h>

#define HID 1024
#define BATCH 128
#define TSTEPS 512
#define NWG 256
#define NTHR 512

typedef __bf16 bf16x4 __attribute__((ext_vector_type(4)));
typedef __bf16 bf16x8 __attribute__((ext_vector_type(8)));
typedef float f32x4 __attribute__((ext_vector_type(4)));

#define ASTORE_U(p,v) __hip_atomic_store((p),(v),__ATOMIC_RELAXED,__HIP_MEMORY_SCOPE_AGENT)
#define ASTORE_F(p,v) __hip_atomic_store((p),(v),__ATOMIC_RELAXED,__HIP_MEMORY_SCOPE_AGENT)
#define ALOAD_U(p)    __hip_atomic_load((p),__ATOMIC_RELAXED,__HIP_MEMORY_SCOPE_AGENT)
#define ALOAD_F(p)    __hip_atomic_load((p),__ATOMIC_RELAXED,__HIP_MEMORY_SCOPE_AGENT)
#define ALOAD_ULL(p)  __hip_atomic_load((p),__ATOMIC_RELAXED,__HIP_MEMORY_SCOPE_AGENT)
#define AADD_U(p,v)   __hip_atomic_fetch_add((p),(v),__ATOMIC_RELAXED,__HIP_MEMORY_SCOPE_AGENT)

__device__ __forceinline__ float sigm(float x){ return 1.f/(1.f+__expf(-x)); }

__device__ __forceinline__ bf16x8 cvt8(const float* __restrict__ p){
  bf16x8 r;
  #pragma unroll
  for (int i=0;i<8;i++) r[i] = (__bf16)p[i];
  return r;
}
__device__ __forceinline__ bf16x8 cvt8s(const float* __restrict__ p, float s){
  bf16x8 r;
  #pragma unroll
  for (int i=0;i<8;i++) r[i] = (__bf16)(p[i]*s);
  return r;
}

// staging layout (round-6 proven): element (u,b) at  (u>>2)*512 + b*4 + (u&3)  [bf16]
__global__ void init_kernel(const float* __restrict__ z,
                            unsigned short* __restrict__ st0,
                            unsigned* __restrict__ bar){
  int i = blockIdx.x*blockDim.x + threadIdx.x;     // 65536 threads
  if (i < 1024) bar[i] = 0u;
  for (int idx = i; idx < BATCH*HID; idx += 65536){
    int blk = idx >> 9, rem = idx & 511, b = rem >> 2, du = rem & 3;
    st0[idx] = __builtin_bit_cast(unsigned short, (__bf16)z[b*HID + blk*4 + du]);
  }
}

// barrier word offsets, each slot in its own 128B line, all < 1024 words (4KB)
#define GRP_CTR(g)  ((g)*32)
#define MID_CTR     256
#define GRP_FLAG(g) (320 + (g)*32)

// M-split structure: wave w owns batches [16w,16w+16) with FULL K=1024;
// weights live in LDS (pre-swizzled B-fragments) -> no per-wave weight VGPRs,
// no cross-wave K-reduction (acc is final per wave), 8-deep A-load ring fits
// the 128-VGPR wall rounds 8-11 established.
__global__ __launch_bounds__(NTHR, 2) void lstm_kernel(
    const float* __restrict__ seq,
    const float* __restrict__ z,
    const float* __restrict__ Wih0, const float* __restrict__ Whh0,
    const float* __restrict__ bih0, const float* __restrict__ bhh0,
    const float* __restrict__ Wih1, const float* __restrict__ Whh1,
    const float* __restrict__ bih1, const float* __restrict__ bhh1,
    const float* __restrict__ Wout, const float* __restrict__ bout,
    float* __restrict__ out,
    unsigned short* __restrict__ st0,
    unsigned short* __restrict__ st1,
    float* __restrict__ predpart,   // [wg][b]
    float* __restrict__ shalf,      // [b] upper-half partial sums
    float* __restrict__ losspart,
    unsigned* __restrict__ bar)
{
  const int tid  = threadIdx.x;
  const int wg   = blockIdx.x;
  const int wid  = tid >> 6;
  const int lane = tid & 63;
  const int u0   = wg << 2;          // owns units [u0,u0+4) in both layers

  // mats: 0=Whh0, 1=Wih1, 2=Whh1, 3=Wfold
  __shared__ bf16x8 wlds[4][32][64];  // 128KB: B-frag for (mat, K-step kt, lane)
  __shared__ float finals2[16*132];   // [col][b], padded stride 132
  __shared__ float pr2[2];
  __shared__ float sb0p[16], sb0f[16], sb1[16];

  const float bout_s = bout[0];

  if (tid < 16) {
    int g = tid >> 2, du = tid & 3;
    int gc = g*HID + u0 + du;
    float bp = bih0[gc] + bhh0[gc];
    sb0p[tid] = bp;                       // layer0 bias, t==0 (pred = 0)
    sb0f[tid] = bp + Wih0[gc]*bout_s;     // layer0 bias + folded b_out term
    sb1[tid]  = bih1[gc] + bhh1[gc];
  }

  const int eb  = tid >> 2;
  const int edu = tid & 3;
  const float wout_u = Wout[u0 + edu];
  float c0 = z[eb*HID + u0 + edu];
  float c1 = c0;
  float lossacc = 0.f;
  float myhalf  = 0.f;                    // thread0 of wg<128: lower-half pred sum

  // ---- weights -> LDS, pre-swizzled to B-fragment layout ----
  // B-frag for global K-step kt': col=lane&15 -> gate*4+du; k = kt'*32+(lane>>4)*8+e.
  // Wave wid loads kt' = wid*4+ktl (k0 = kt'*32 + ksub), same cvt8 code as the
  // proven round-6 register path.
  const int bcol = lane & 15;
  const int gcol = (bcol >> 2)*HID + u0 + (bcol & 3);
  const int ksub = (lane >> 4) << 3;
  {
    const float wih0c = Wih0[gcol];
    #pragma unroll
    for (int ktl=0; ktl<4; ++ktl) {
      int k0  = (wid << 7) + (ktl << 5) + ksub;
      int ktg = (wid << 2) + ktl;
      wlds[0][ktg][lane] = cvt8(Whh0 + gcol*HID + k0);
      wlds[1][ktg][lane] = cvt8(Wih1 + gcol*HID + k0);
      wlds[2][ktg][lane] = cvt8(Whh1 + gcol*HID + k0);
      wlds[3][ktg][lane] = cvt8s(Wout + k0, wih0c);
    }
  }
  __syncthreads();                        // wlds + sb* visible to all waves

  f32x4 accG0{0,0,0,0}, accG1{0,0,0,0};
  unsigned gen = 0;

  // A-frag addressing (M-split): batch b = wid*16 + (lane&15); k = kt*32+(lane>>4)*8+e
  // staging linear = (k>>2)*512 + b*4 + (k&3): lo 8B at (kt*8+2*(lane>>4))*512 + b*4,
  // hi 8B at +512. sc1 (coherence-point) loads, 8-deep ring in flight.
  const int hi2 = (lane >> 4) << 1;
  const int bb4 = ((wid << 4) + (lane & 15)) << 2;

  auto ldfrag = [&](const unsigned short* __restrict__ src, int kt)->bf16x8{
    const unsigned short* p = src + (size_t)(((kt << 3) + hi2) * 512) + bb4;
    unsigned long long lo64 = ALOAD_ULL((const unsigned long long*)p);
    unsigned long long hi64 = ALOAD_ULL((const unsigned long long*)(p + 512));
    bf16x4 lo = __builtin_bit_cast(bf16x4, lo64);
    bf16x4 hi = __builtin_bit_cast(bf16x4, hi64);
    return __builtin_shufflevector(lo, hi, 0,1,2,3,4,5,6,7);
  };

  auto do_pass = [&](const unsigned short* __restrict__ src, int matA, int matB,
                     f32x4& accA, f32x4& accB){
    bf16x8 af[8];
    #pragma unroll
    for (int i=0;i<8;i++) af[i] = ldfrag(src, i);
    #pragma unroll
    for (int kt=0; kt<32; ++kt){
      bf16x8 a = af[kt & 7];
      accA = __builtin_amdgcn_mfma_f32_16x16x32_bf16(a, wlds[matA][kt][lane], accA, 0, 0, 0);
      accB = __builtin_amdgcn_mfma_f32_16x16x32_bf16(a, wlds[matB][kt][lane], accB, 0, 0, 0);
      if (kt < 24) af[kt & 7] = ldfrag(src, kt + 8);   // refill after last use
    }
  };

  // acc is FINAL (full K per wave): scatter to finals2[col][b] (+bias), one sync.
  // C layout (m89-verified): col=lane&15, row=(lane>>4)*4+reg -> b = wid*16+row.
  auto publish = [&](f32x4& acc, const float* sbias){
    float bias = sbias[lane & 15];
    int base = (lane & 15)*132 + (wid << 4) + ((lane >> 4) << 2);
    #pragma unroll
    for (int e=0;e<4;e++) finals2[base + e] = acc[e] + bias;
    __syncthreads();
    acc = f32x4{0,0,0,0};
  };

  auto elementwise = [&](float& c, unsigned short* __restrict__ stdst, bool dopred){
    float gi = finals2[(edu   )*132 + eb];
    float gf = finals2[(edu+ 4)*132 + eb];
    float gg = finals2[(edu+ 8)*132 + eb];
    float go = finals2[(edu+12)*132 + eb];
    float fi = sigm(gi), ff = sigm(gf), fo = sigm(go);
    c = ff*c + fi*tanhf(gg);
    float h = fo*tanhf(c);
    unsigned h16 = (unsigned)__builtin_bit_cast(unsigned short, (__bf16)h);
    unsigned other = (unsigned)__shfl_xor((int)h16, 1);
    if (!(tid & 1)) {
      unsigned word = h16 | (other << 16);            // coalesced dword at elem tid
      ASTORE_U((unsigned*)(stdst + wg*512 + tid), word);
    }
    if (dopred){
      float pv = h * wout_u;
      pv += __shfl_xor(pv, 1);
      pv += __shfl_xor(pv, 2);
      if (edu == 0) ASTORE_F(&predpart[wg*128 + eb], pv);
    }
  };

  // round-6-proven barrier: padded counters, fan-out release, sc1 protocol.
  auto grid_barrier = [&](){
    __syncthreads();                       // drains vmcnt -> sc1 stores at L3
    ++gen;
    if (tid == 0) {
      unsigned old = AADD_U(&bar[GRP_CTR(wg & 7)], 1u);
      if (old == gen*32u - 1u) {
        unsigned r = AADD_U(&bar[MID_CTR], 1u);
        if (r == gen*8u - 1u) {
          #pragma unroll
          for (int g2=0; g2<8; ++g2) ASTORE_U(&bar[GRP_FLAG(g2)], gen);
        }
      }
      while (ALOAD_U(&bar[GRP_FLAG(wg & 7)]) < gen)
        __builtin_amdgcn_s_sleep(4);
    }
    __syncthreads();
  };

  // ---- prologue: accG0 = z@Whh0 (gates0[0]); accG1 = z@Whh1 (carry) ----
  do_pass(st0, 0, 2, accG0, accG1);
  grid_barrier();                          // all WGs consumed z-staging
  publish(accG0, sb0p);
  elementwise(c0, st0, false);             // h0[0] -> st0
  grid_barrier();                          // publish h0[0]

  for (int t=0; t<TSTEPS; ++t) {
    // ---- Phase A: gates1[t] completes (h0@Wih1); gates0[t+1] h0-part (h0@Whh0) ----
    do_pass(st0, 1, 0, accG1, accG0);
    float oh = 0.f;
    if (t > 0 && wg < BATCH && tid == 0) oh = ALOAD_F(&shalf[wg]);   // early load
    publish(accG1, sb1);
    if (t > 0 && wg < BATCH && tid == 0) {
      float pred = myhalf + oh + bout_s;                   // finalize pred[t-1]
      out[1 + wg*TSTEPS + (t-1)] = pred;
      float d = seq[wg*TSTEPS + (t-1)] - pred;
      lossacc += d*d;
    }
    elementwise(c1, st1, true);            // h1[t] + pred partials
    grid_barrier();                        // publish h1[t], predpart

    // ---- Phase B: gates0[t+1] completes (h1@Wfold); gates1[t+1] h1-part (h1@Whh1) ----
    float hred = 0.f;
    if (tid < 128)
      hred = ALOAD_F(&predpart[((wg >> 7)*128 + tid)*128 + (wg & 127)]);  // early
    do_pass(st1, 3, 2, accG0, accG1);
    hred += __shfl_xor(hred, 1);  hred += __shfl_xor(hred, 2);
    hred += __shfl_xor(hred, 4);  hred += __shfl_xor(hred, 8);
    hred += __shfl_xor(hred, 16); hred += __shfl_xor(hred, 32);
    if (tid == 0)  pr2[0] = hred;
    if (tid == 64) pr2[1] = hred;
    publish(accG0, sb0f);                  // internal sync publishes pr2 to tid0
    if (tid == 0) {
      float hs = pr2[0] + pr2[1];
      if (wg >= BATCH) ASTORE_F(&shalf[wg - BATCH], hs);
      else             myhalf = hs;
    }
    elementwise(c0, st0, false);           // h0[t+1]
    grid_barrier();                        // publish h0[t+1], shalf
  }

  // ---- epilogue: last pred + loss ----
  if (wg < BATCH && tid == 0) {
    float oh2 = ALOAD_F(&shalf[wg]);
    float pred = myhalf + oh2 + bout_s;
    out[1 + wg*TSTEPS + (TSTEPS-1)] = pred;
    float d = seq[wg*TSTEPS + (TSTEPS-1)] - pred;
    lossacc += d*d;
    ASTORE_F(&losspart[wg], lossacc);
  }
  grid_barrier();
  if (wg == 0) {
    float v = 0.f;
    if (tid < BATCH) v = ALOAD_F(&losspart[tid]);
    v += __shfl_xor(v, 1);  v += __shfl_xor(v, 2);
    v += __shfl_xor(v, 4);  v += __shfl_xor(v, 8);
    v += __shfl_xor(v, 16); v += __shfl_xor(v, 32);
    if (tid == 0)  pr2[0] = v;
    if (tid == 64) pr2[1] = v;
    __syncthreads();
    if (tid == 0) out[0] = (pr2[0] + pr2[1]) * (1.f/65536.f);
  }
}

extern "C" void kernel_launch(void* const* d_in, const int* in_sizes, int n_in,
                              void* d_out, int out_size, void* d_ws, size_t ws_size,
                              hipStream_t stream)
{
  const float* seq  = (const float*)d_in[0];
  const float* z    = (const float*)d_in[1];
  const float* Wih0 = (const float*)d_in[2];
  const float* Whh0 = (const float*)d_in[3];
  const float* bih0 = (const float*)d_in[4];
  const float* bhh0 = (const float*)d_in[5];
  const float* Wih1 = (const float*)d_in[6];
  const float* Whh1 = (const float*)d_in[7];
  const float* bih1 = (const float*)d_in[8];
  const float* bhh1 = (const float*)d_in[9];
  const float* Wout = (const float*)d_in[10];
  const float* bout = (const float*)d_in[11];
  float* out = (float*)d_out;

  // round-6-proven layout
  char* ws = (char*)d_ws;
  unsigned short* st0 = (unsigned short*)(ws);                    // 256KB @ 0
  unsigned short* st1 = (unsigned short*)(ws + 256*1024);         // 256KB @ 256K
  unsigned* bar   = (unsigned*)(ws + 512*1024);                   // 4KB  @ 512K
  float* predpart = (float*)(ws + 516*1024);                      // 128KB @ 516K
  float* shalf    = (float*)(ws + 644*1024);                      // 512B @ 644K
  float* losspart = (float*)(ws + 644*1024 + 512);                // 512B

  hipLaunchKernelGGL(init_kernel, dim3(256), dim3(256), 0, stream, z, st0, bar);

  void* args[] = { (void*)&seq, (void*)&z, (void*)&Wih0, (void*)&Whh0, (void*)&bih0, (void*)&bhh0,
                   (void*)&Wih1, (void*)&Whh1, (void*)&bih1, (void*)&bhh1, (void*)&Wout, (void*)&bout,
                   (void*)&out, (void*)&st0, (void*)&st1, (void*)&predpart, (void*)&shalf,
                   (void*)&losspart, (void*)&bar };
  hipLaunchCooperativeKernel((void*)lstm_kernel, dim3(NWG), dim3(NTHR), args, 0u, stream);
}